// Round 10
// baseline (29.125 us; speedup 1.0000x reference)
//
#include <hip/hip_runtime.h>

// GPTQ W4A32 linear, bf16 MFMA + magic-mantissa dequant, SINGLE DISPATCH.
// out(16,11008) = x(16,4096) @ W,  W[k][n] = s[g][n]*(w4[k][n] - z4[g][n]).
// bf16 bits (0x4380|w) == 256+2w exactly -> MFMA on raw nibbles gives
// P_raw = 256*X + 2*P per group (X = group-sum of bf16-rounded x):
// out += (s/2)*P_raw - s*(128+z)*X.  Mask-trick nibble order k={0,4,1,5,2,6,3,7}
// matches cvt_pk pair order in the in-register A-fragment build.
//
// Structure (post R4..R9 scoreboard): grid 688 x 512thr, BLOCKN=16.
// 8 waves split K (4 groups each); A-frags built in-register from x
// (lane reads 32B of its row per tile; one 128B line per row per tile);
// X published via same-wave LDS (no barrier); one LDS cross-wave reduce;
// direct store. No prep kernel, no partials, no atomics, no fences (R5!),
// no manual pipelining (R7!). XCD swizzle: 688 = 8*86 bijective.

#define M_DIM 16
#define K_DIM 4096
#define N_DIM 11008
#define GS 128
#define NG (K_DIM / GS)          // 32 groups
#define WAVES 8
#define GPW (NG / WAVES)         // 4 groups per wave
#define NTHREADS 512
#define NBLK (N_DIM / 16)        // 688

typedef __attribute__((ext_vector_type(8))) short short8;
typedef __attribute__((ext_vector_type(4))) float f32x4;

__device__ __forceinline__ float bfl(unsigned w) {
    union { unsigned u; float f; } c; c.u = w << 16; return c.f;
}
__device__ __forceinline__ float bfh(unsigned w) {
    union { unsigned u; float f; } c; c.u = w & 0xFFFF0000u; return c.f;
}

__global__ __launch_bounds__(NTHREADS) void qlin_one(
    const float* __restrict__ x,
    const int*   __restrict__ qweight,
    const float* __restrict__ scales,
    const int*   __restrict__ qzeros,
    float*       __restrict__ out)
{
    __shared__ __align__(16) float Xl[NG * 16];      // 2 KiB
    __shared__ __align__(16) f32x4 red[WAVES * 64];  // 8 KiB

    const int tid  = threadIdx.x;
    const int lane = tid & 63, wave = tid >> 6;
    const int lmod = lane & 15, lhi = lane >> 4;
    // XCD-aware bijective swizzle: adjacent n-strips share an XCD's L2
    const int nb   = (blockIdx.x & 7) * (NBLK / 8) + (blockIdx.x >> 3);
    const int n    = nb * 16 + lmod;
    const int zsh  = (n & 7) * 4;
    const float* xrow = x + (size_t)lmod * K_DIM;

    f32x4 outacc = {0.f, 0.f, 0.f, 0.f};

#pragma unroll
    for (int g = 0; g < GPW; ++g) {
        const int G = wave * GPW + g;
        const float s = scales[(size_t)G * N_DIM + n];
        const unsigned zq =
            (unsigned)qzeros[(size_t)G * (N_DIM / 8) + (n >> 3)];

        f32x4 acc = {0.f, 0.f, 0.f, 0.f};
        float xs = 0.f;
#pragma unroll
        for (int t = 0; t < 4; ++t) {
            const int T = G * 4 + t;
            // A-fragment in-register: lane reads x[lmod][T*32 + lhi*8 .. +7]
            const float4* xp = (const float4*)(xrow + T * 32 + lhi * 8);
            const float4 v0 = xp[0], v1 = xp[1];
            union { short8 sv; unsigned u[4]; } pk;
            asm("v_cvt_pk_bf16_f32 %0, %1, %2" : "=v"(pk.u[0]) : "v"(v0.x), "v"(v1.x));
            asm("v_cvt_pk_bf16_f32 %0, %1, %2" : "=v"(pk.u[1]) : "v"(v0.y), "v"(v1.y));
            asm("v_cvt_pk_bf16_f32 %0, %1, %2" : "=v"(pk.u[2]) : "v"(v0.z), "v"(v1.z));
            asm("v_cvt_pk_bf16_f32 %0, %1, %2" : "=v"(pk.u[3]) : "v"(v0.w), "v"(v1.w));

            const unsigned q =
                (unsigned)qweight[(size_t)(T * 4 + lhi) * N_DIM + n];
            union { short8 v; unsigned u[4]; } b;
            b.u[0] = ( q        & 0x000F000Fu) | 0x43804380u;
            b.u[1] = ((q >> 4)  & 0x000F000Fu) | 0x43804380u;
            b.u[2] = ((q >> 8)  & 0x000F000Fu) | 0x43804380u;
            b.u[3] = ((q >> 12) & 0x000F000Fu) | 0x43804380u;
            acc = __builtin_amdgcn_mfma_f32_16x16x32_bf16(pk.sv, b.v, acc, 0, 0, 0);

            // exact sum of the rounded values (must match MFMA input bits)
#pragma unroll
            for (int p = 0; p < 4; ++p) xs += bfl(pk.u[p]) + bfh(pk.u[p]);
        }
        // X[G][m=lmod]: reduce over lhi (each lane summed 32 of 128 k)
        xs += __shfl_xor(xs, 16, 64);
        xs += __shfl_xor(xs, 32, 64);
        if (lane < 16) Xl[G * 16 + lane] = xs;   // same-wave publish
        const f32x4 x4 = *(const f32x4*)&Xl[G * 16 + lhi * 4];

        const float z  = (float)((zq >> zsh) & 15u);
        const float s2 = 0.5f * s;
        const float zc = -s * (128.0f + z);
#pragma unroll
        for (int r = 0; r < 4; ++r)
            outacc[r] = fmaf(s2, acc[r], fmaf(zc, x4[r], outacc[r]));
    }

    // ---- cross-wave K reduction in LDS, wave 0 writes out
    red[wave * 64 + lane] = outacc;
    __syncthreads();
    if (wave == 0) {
        f32x4 sum = red[lane];
#pragma unroll
        for (int w = 1; w < WAVES; ++w) {
            const f32x4 rv = red[w * 64 + lane];
#pragma unroll
            for (int r = 0; r < 4; ++r) sum[r] += rv[r];
        }
#pragma unroll
        for (int r = 0; r < 4; ++r)
            out[(size_t)(lhi * 4 + r) * N_DIM + n] = sum[r];
    }
}

extern "C" void kernel_launch(void* const* d_in, const int* in_sizes, int n_in,
                              void* d_out, int out_size, void* d_ws, size_t ws_size,
                              hipStream_t stream) {
    const float* x       = (const float*)d_in[0];
    const int*   qweight = (const int*)d_in[1];
    const float* scales  = (const float*)d_in[2];
    const int*   qzeros  = (const int*)d_in[3];
    float*       out     = (float*)d_out;

    qlin_one<<<NBLK, NTHREADS, 0, stream>>>(x, qweight, scales, qzeros, out);
}

// Round 11
// 18.091 us; speedup vs baseline: 1.6100x; 1.6100x over previous
//
#include <hip/hip_runtime.h>

// GPTQ W4A32 linear via bf16 MFMA, magic-mantissa dequant, fused x-staging.
// out(16,11008) = x(16,4096) @ W,  W[k][n] = s[g][n]*(w4[k][n] - z4[g][n]).
// bf16 bits (0x4380|w) == 256+2w exactly -> MFMA on raw nibbles gives
// P_raw = 256*X + 2*P per group (X = group-sum of bf16-rounded x):
// out += (s/2)*P_raw - s*(128+z)*X.  Mask-trick nibble order k={0,4,1,5,2,6,3,7}
// per 8; x staged to LDS with same permutation, XOR-swizzled (^(m&7)<<4).
//
// R11 = R4's EXACT kernel body/grid (best measured: 16.0us; every structural
// deviation in R5-R10 lost) with only the epilogue changed: partials+reduce
// dispatch replaced by fp32 atomicAdd into stream-memset d_out (single real
// dispatch). R8 validated this epilogue's correctness; here it rides on R4's
// verified TLP config (KSPLIT=8, 1376 blocks, 16KB LDS, 256thr).
// No device-scope fences (R5: 320us). No manual pipelining/launch-bounds
// caps (R7: spills). No TLP reduction (R9/R10: +6..13us).

#define M_DIM 16
#define K_DIM 4096
#define N_DIM 11008
#define GS 128
#define KSPLIT 8
#define KC (K_DIM / KSPLIT)      // 512 k per block chunk
#define GPC (KC / GS)            // 4 groups per chunk
#define BLOCKN 64                // 4 waves x 16 n
#define NTHREADS 256

typedef __attribute__((ext_vector_type(8))) short short8;
typedef __attribute__((ext_vector_type(4))) float f32x4;

__device__ __forceinline__ float bfl(unsigned w) {
    union { unsigned u; float f; } c; c.u = w << 16; return c.f;
}
__device__ __forceinline__ float bfh(unsigned w) {
    union { unsigned u; float f; } c; c.u = w & 0xFFFF0000u; return c.f;
}

__global__ __launch_bounds__(NTHREADS) void qlin_fused(
    const float* __restrict__ x,
    const int*   __restrict__ qweight,
    const float* __restrict__ scales,
    const int*   __restrict__ qzeros,
    float*       __restrict__ out)    // pre-zeroed; atomic accumulate
{
    __shared__ __align__(16) unsigned short xs[M_DIM * KC];  // 16 KiB swizzled
    __shared__ __align__(16) float Xl[GPC * 16];

    const int tid  = threadIdx.x;
    const int lane = tid & 63, wave = tid >> 6;
    const int lmod = lane & 15, lhi = lane >> 4;
    const int n    = blockIdx.x * BLOCKN + wave * 16 + lmod;
    const int swzA = (lmod & 7) << 4;
    const int zsh  = (n & 7) * 4;

    const int ky0 = blockIdx.y * KC;
    const int G0 = ky0 / GS, rowbase = ky0 >> 3;

    // ---- stage x[16][KC]: f32 -> bf16 (RNE), permuted, swizzled (R4 loop)
#pragma unroll
    for (int i = 0; i < (M_DIM * KC / 8) / NTHREADS; ++i) {   // 4 iters
        const int idx = i * NTHREADS + tid;
        const int m  = idx >> 6;          // KC/8 == 64 chunks per row
        const int cc = idx & 63;
        const float4* xp =
            (const float4*)(x + (size_t)m * K_DIM + ky0 + cc * 8);
        const float4 v0 = xp[0], v1 = xp[1];
        union { short8 s; unsigned u[4]; } pk;
        asm("v_cvt_pk_bf16_f32 %0, %1, %2" : "=v"(pk.u[0]) : "v"(v0.x), "v"(v1.x));
        asm("v_cvt_pk_bf16_f32 %0, %1, %2" : "=v"(pk.u[1]) : "v"(v0.y), "v"(v1.y));
        asm("v_cvt_pk_bf16_f32 %0, %1, %2" : "=v"(pk.u[2]) : "v"(v0.z), "v"(v1.z));
        asm("v_cvt_pk_bf16_f32 %0, %1, %2" : "=v"(pk.u[3]) : "v"(v0.w), "v"(v1.w));
        const int byte = ((m * KC + cc * 8) * 2) ^ ((m & 7) << 4);
        *(short8*)((char*)xs + byte) = pk.s;
    }
    __syncthreads();

    // ---- X[g][m] = group-sum of staged bf16 (wave g handles group g)
    if (wave < GPC) {
        const int g = wave;
        float xv = 0.f;
#pragma unroll
        for (int q = 0; q < 4; ++q) {
            const int byte =
                ((lmod * KC + g * GS + lhi * 32 + q * 8) * 2) ^ swzA;
            union { short8 s; unsigned u[4]; } a;
            a.s = *(const short8*)((const char*)xs + byte);
#pragma unroll
            for (int p = 0; p < 4; ++p) xv += bfl(a.u[p]) + bfh(a.u[p]);
        }
        xv += __shfl_xor(xv, 16, 64);
        xv += __shfl_xor(xv, 32, 64);
        if (lane < 16) Xl[g * 16 + lane] = xv;
    }
    __syncthreads();

    // ---- MFMA over GPC groups; qweight loads left to the compiler to hoist
    f32x4 outacc = {0.f, 0.f, 0.f, 0.f};
#pragma unroll
    for (int g = 0; g < GPC; ++g) {
        const float s = scales[(size_t)(G0 + g) * N_DIM + n];
        const unsigned zq =
            (unsigned)qzeros[(size_t)(G0 + g) * (N_DIM / 8) + (n >> 3)];
        f32x4 acc = {0.f, 0.f, 0.f, 0.f};
#pragma unroll
        for (int t = 0; t < 4; ++t) {
            const unsigned q = (unsigned)
                qweight[(size_t)(rowbase + g * 16 + t * 4 + lhi) * N_DIM + n];
            union { short8 v; unsigned u[4]; } b;
            b.u[0] = ( q        & 0x000F000Fu) | 0x43804380u;
            b.u[1] = ((q >> 4)  & 0x000F000Fu) | 0x43804380u;
            b.u[2] = ((q >> 8)  & 0x000F000Fu) | 0x43804380u;
            b.u[3] = ((q >> 12) & 0x000F000Fu) | 0x43804380u;
            const int byte =
                ((lmod * KC + g * GS + t * 32 + lhi * 8) * 2) ^ swzA;
            const short8 a = *(const short8*)((const char*)xs + byte);
            acc = __builtin_amdgcn_mfma_f32_16x16x32_bf16(a, b.v, acc, 0, 0, 0);
        }
        const f32x4 x4 = *(const f32x4*)&Xl[g * 16 + lhi * 4];
        const float z  = (float)((zq >> zsh) & 15u);
        const float s2 = 0.5f * s;
        const float zc = -s * (128.0f + z);
#pragma unroll
        for (int r = 0; r < 4; ++r)
            outacc[r] = fmaf(s2, acc[r], fmaf(zc, x4[r], outacc[r]));
    }

    // ---- accumulate into pre-zeroed out (KSPLIT adds per element; no fence)
#pragma unroll
    for (int r = 0; r < 4; ++r)
        atomicAdd(&out[(size_t)(lhi * 4 + r) * N_DIM + n], outacc[r]);
}

extern "C" void kernel_launch(void* const* d_in, const int* in_sizes, int n_in,
                              void* d_out, int out_size, void* d_ws, size_t ws_size,
                              hipStream_t stream) {
    const float* x       = (const float*)d_in[0];
    const int*   qweight = (const int*)d_in[1];
    const float* scales  = (const float*)d_in[2];
    const int*   qzeros  = (const int*)d_in[3];
    float*       out     = (float*)d_out;

    hipMemsetAsync(out, 0, (size_t)out_size * sizeof(float), stream);
    dim3 grid(N_DIM / BLOCKN, KSPLIT);              // (172, 8)
    qlin_fused<<<grid, NTHREADS, 0, stream>>>(x, qweight, scales, qzeros, out);
}